// Round 1
// baseline (3099.771 us; speedup 1.0000x reference)
//
#include <hip/hip_runtime.h>
#include <hip/hip_bf16.h>

#define NN 8192
#define NCOLS 101      // y + 100 probes
#define CPW 112        // compute columns (7 x 16)
#define CPAD 128       // staged columns (zero-padded)
#define BM 64
#define BK 64
#define KSPL 4
#define KCH (NN / KSPL)    // 2048
#define NSTEP (KCH / BK)   // 32
#define PITER 30

typedef __attribute__((ext_vector_type(8))) short bf16x8;
typedef __attribute__((ext_vector_type(4))) float f32x4;

__device__ __forceinline__ unsigned short f2bf(float f) {
  __hip_bfloat16 h = __float2bfloat16(f);
  return *reinterpret_cast<unsigned short*>(&h);
}

__device__ __forceinline__ void async_copy16(const void* g, void* l) {
  __builtin_amdgcn_global_load_lds(
      (const __attribute__((address_space(1))) unsigned int*)g,
      (__attribute__((address_space(3))) unsigned int*)l, 16, 0, 0);
}

// valid result on thread 0 only
__device__ __forceinline__ float block_sum(float v) {
  #pragma unroll
  for (int o = 32; o > 0; o >>= 1) v += __shfl_down(v, o);
  __shared__ float sw[4];
  int w = threadIdx.x >> 6;
  if ((threadIdx.x & 63) == 0) sw[w] = v;
  __syncthreads();
  float r = 0.f;
  if (threadIdx.x < 4) r = sw[threadIdx.x];
  r += __shfl_down(r, 2);
  r += __shfl_down(r, 1);
  return r;
}

// ---------------- GEMM: Vpart[kz] = K[rb rows] @ P (bf16 MFMA) ----------------
// LDS layout: sA[row][kslot] where kslot = seg ^ (row&7)  (seg = 16B segment of 8 bf16)
// This keeps global_load_lds's "base + lane*16" contiguity AND makes ds_read_b128
// of fragments hit all 32 banks 2-way (free) instead of 16-way.
__global__ __launch_bounds__(256, 2) void gemm_kernel(
    const unsigned short* __restrict__ Kb,
    const unsigned short* __restrict__ Pb,
    float* __restrict__ Vp) {
  __shared__ __align__(16) unsigned short sA[BM * BK];     // 8 KB
  __shared__ __align__(16) unsigned short sB[CPAD * BK];   // 16 KB
  __shared__ __align__(16) float sC[BM * 113];             // 28.9 KB (113 kills xpose conflicts)

  int bx = blockIdx.x;
  int rb = bx & 127;
  int kz = bx >> 7;
  int tid = threadIdx.x;
  int lane = tid & 63;
  int w = tid >> 6;
  int r0 = rb * BM;
  int k0 = kz * KCH;
  int lrow = lane >> 3;   // 0..7
  int lseg = lane & 7;    // LDS 16B slot within row

  f32x4 acc[7];
  #pragma unroll
  for (int i = 0; i < 7; ++i) acc[i] = (f32x4){0.f, 0.f, 0.f, 0.f};

  int mm = lane & 15;
  int quad = lane >> 4;

  for (int s = 0; s < NSTEP; ++s) {
    int kk = k0 + s * BK;
    int gseg = lseg ^ lrow;  // fetch permuted segment so LDS slot lseg holds seg lseg^(row&7)
    #pragma unroll
    for (int q = 0; q < 2; ++q) {  // A: wave w stages rows w*16 + q*8 + lrow
      int rl = w * 16 + q * 8 + lrow;
      const unsigned short* g = Kb + (size_t)(r0 + rl) * NN + kk + gseg * 8;
      async_copy16(g, (char*)sA + (size_t)(w * 16 + q * 8) * 128);
    }
    #pragma unroll
    for (int q = 0; q < 4; ++q) {  // B: wave w stages cols w*32 + q*8 + lrow
      int cl = w * 32 + q * 8 + lrow;
      const unsigned short* g = Pb + (size_t)cl * NN + kk + gseg * 8;
      async_copy16(g, (char*)sB + (size_t)(w * 32 + q * 8) * 128);
    }
    __syncthreads();
    const bf16x8* sAv = (const bf16x8*)sA;
    const bf16x8* sBv = (const bf16x8*)sB;
    int arow = w * 16 + mm;
    #pragma unroll
    for (int kh = 0; kh < 2; ++kh) {
      int sidx = kh * 4 + quad;
      bf16x8 aF = sAv[arow * 8 + (sidx ^ (arow & 7))];
      #pragma unroll
      for (int ct = 0; ct < 7; ++ct) {
        int bcol = ct * 16 + mm;
        bf16x8 bF = sBv[bcol * 8 + (sidx ^ (bcol & 7))];
        acc[ct] = __builtin_amdgcn_mfma_f32_16x16x32_bf16(aF, bF, acc[ct], 0, 0, 0);
      }
    }
    __syncthreads();
  }
  // epilogue: transpose through LDS, store column-major V partials
  #pragma unroll
  for (int ct = 0; ct < 7; ++ct)
    #pragma unroll
    for (int r = 0; r < 4; ++r)
      sC[(w * 16 + quad * 4 + r) * 113 + ct * 16 + mm] = acc[ct][r];
  __syncthreads();
  float* Vout = Vp + (size_t)kz * ((size_t)CPW * NN);
  for (int idx = tid; idx < BM * CPW; idx += 256) {
    int col = idx >> 6;
    int row = idx & 63;
    if (col < NCOLS)
      Vout[(size_t)col * NN + r0 + row] = sC[row * 113 + col];
  }
}

// ---------------- V = sum of 4 partials; pv[c] += sum(P.*V) ----------------
__global__ void reduce_pv_kernel(const float* __restrict__ Vp,
                                 const float* __restrict__ P,
                                 float* __restrict__ V,
                                 float* __restrict__ pv) {
  const size_t SPL = (size_t)CPW * NN;
  int c = blockIdx.y;
  size_t off = (size_t)c * NN + blockIdx.x * 1024 + threadIdx.x * 4;
  float4 a = *(const float4*)(Vp + off);
  float4 b = *(const float4*)(Vp + SPL + off);
  float4 d = *(const float4*)(Vp + 2 * SPL + off);
  float4 e = *(const float4*)(Vp + 3 * SPL + off);
  float4 v;
  v.x = a.x + b.x + d.x + e.x;
  v.y = a.y + b.y + d.y + e.y;
  v.z = a.z + b.z + d.z + e.z;
  v.w = a.w + b.w + d.w + e.w;
  *(float4*)(V + off) = v;
  float4 p = *(const float4*)(P + off);
  float dot = p.x * v.x + p.y * v.y + p.z * v.z + p.w * v.w;
  float tot = block_sum(dot);
  if (threadIdx.x == 0) atomicAdd(pv + c, tot);
}

// ---------------- alpha; X0 += a*P(:,0); R -= a*V; rs_new += |R|^2 ----------------
__global__ void update1_kernel(const float* __restrict__ V,
                               const float* __restrict__ P,
                               float* __restrict__ R,
                               float* __restrict__ X0,
                               const float* __restrict__ pv,
                               const float* __restrict__ rs,
                               float* __restrict__ rs_new,
                               float* __restrict__ alphas) {
  int c = blockIdx.y;
  float alpha = rs[c] / pv[c];
  size_t off = (size_t)c * NN + blockIdx.x * 1024 + threadIdx.x * 4;
  float4 r = *(float4*)(R + off);
  float4 v = *(const float4*)(V + off);
  r.x -= alpha * v.x; r.y -= alpha * v.y; r.z -= alpha * v.z; r.w -= alpha * v.w;
  *(float4*)(R + off) = r;
  if (c == 0) {
    size_t xo = blockIdx.x * 1024 + threadIdx.x * 4;
    float4 x = *(float4*)(X0 + xo);
    float4 p = *(const float4*)(P + off);
    x.x += alpha * p.x; x.y += alpha * p.y; x.z += alpha * p.z; x.w += alpha * p.w;
    *(float4*)(X0 + xo) = x;
  }
  float rn = r.x * r.x + r.y * r.y + r.z * r.z + r.w * r.w;
  float tot = block_sum(rn);
  if (threadIdx.x == 0) {
    atomicAdd(rs_new + c, tot);
    if (blockIdx.x == 0) alphas[c] = alpha;
  }
}

// ---------------- beta; P = R + b*P; Pb = bf16(P) ----------------
__global__ void update2_kernel(const float* __restrict__ R,
                               float* __restrict__ P,
                               unsigned short* __restrict__ Pb,
                               const float* __restrict__ rs,
                               const float* __restrict__ rs_new,
                               float* __restrict__ betas) {
  int c = blockIdx.y;
  float beta = rs_new[c] / rs[c];
  size_t off = (size_t)c * NN + blockIdx.x * 1024 + threadIdx.x * 4;
  float4 r = *(const float4*)(R + off);
  float4 p = *(float4*)(P + off);
  p.x = r.x + beta * p.x; p.y = r.y + beta * p.y;
  p.z = r.z + beta * p.z; p.w = r.w + beta * p.w;
  *(float4*)(P + off) = p;
  ushort4 u;
  u.x = f2bf(p.x); u.y = f2bf(p.y); u.z = f2bf(p.z); u.w = f2bf(p.w);
  *(ushort4*)(Pb + off) = u;
  if (threadIdx.x == 0 && blockIdx.x == 0) betas[c] = beta;
}

// ---------------- init ----------------
__global__ void cast_k_kernel(const float* __restrict__ K, unsigned short* __restrict__ Kb) {
  size_t i = ((size_t)blockIdx.x * 256 + threadIdx.x) * 4;
  size_t stride = (size_t)gridDim.x * 1024;
  for (; i < (size_t)NN * NN; i += stride) {
    float4 f = *(const float4*)(K + i);
    ushort4 u;
    u.x = f2bf(f.x); u.y = f2bf(f.y); u.z = f2bf(f.z); u.w = f2bf(f.w);
    *(ushort4*)(Kb + i) = u;
  }
}

__global__ void init_vec_kernel(const float* __restrict__ y, const float* __restrict__ Z,
                                float* __restrict__ P, float* __restrict__ R,
                                unsigned short* __restrict__ Pb) {
  int c = blockIdx.y;
  int i = blockIdx.x * 256 + threadIdx.x;
  float val = (c == 0) ? y[i] : Z[(size_t)i * 100 + (c - 1)];
  size_t off = (size_t)c * NN + i;
  P[off] = val;
  R[off] = val;
  Pb[off] = f2bf(val);
}

__global__ void init_misc_kernel(float* __restrict__ X0, float* __restrict__ smalls,
                                 unsigned short* __restrict__ Pbpad) {
  const int total = 8192 + 15488 + 27 * NN;
  for (int t = blockIdx.x * 256 + threadIdx.x; t < total; t += gridDim.x * 256) {
    if (t < 8192) X0[t] = 0.f;
    else if (t < 8192 + 15488) smalls[t - 8192] = 0.f;
    else Pbpad[t - (8192 + 15488)] = 0;
  }
}

__global__ void init_rs_kernel(const float* __restrict__ y, float* __restrict__ rs0) {
  int t = threadIdx.x;
  float s = 0.f;
  for (int i = t; i < NN; i += 256) { float v = y[i]; s += v * v; }
  float tot = block_sum(s);
  if (t == 0) rs0[0] = tot;
  if (t >= 1 && t <= 100) rs0[t] = (float)NN;  // Z columns are +-1: |col|^2 = N exactly
}

// ---------------- final: ydot + per-probe tridiagonal eigensolve (tql2, row-0 only) ----------------
__global__ void final_kernel(const float* __restrict__ y, const float* __restrict__ X0,
                             const float* __restrict__ alphas, const float* __restrict__ betas,
                             float* __restrict__ out) {
  __shared__ float sdata[256];
  int t = threadIdx.x;
  float s = 0.f;
  for (int i = t; i < NN; i += 256) s += y[i] * X0[i];
  sdata[t] = s;
  __syncthreads();
  for (int st = 128; st > 0; st >>= 1) {
    if (t < st) sdata[t] += sdata[t + st];
    __syncthreads();
  }
  float ydot = sdata[0];
  __syncthreads();

  float quad = 0.f;
  if (t < 100) {
    int c = t + 1;
    float d[PITER], e[PITER], z[PITER];
    for (int i = 0; i < PITER; ++i) {
      float a = alphas[i * 128 + c];
      d[i] = 1.f / a;
      if (i > 0) {
        float ap = alphas[(i - 1) * 128 + c];
        float bp = betas[(i - 1) * 128 + c];
        d[i] += bp / ap;
        e[i - 1] = sqrtf(bp) / ap;
      }
      z[i] = 0.f;
    }
    e[PITER - 1] = 0.f;
    z[0] = 1.f;
    for (int l = 0; l < PITER; ++l) {
      int iter = 0;
      int m;
      do {
        for (m = l; m < PITER - 1; ++m) {
          float dd = fabsf(d[m]) + fabsf(d[m + 1]);
          if (fabsf(e[m]) <= 1.19209e-07f * dd) break;
        }
        if (m != l) {
          if (iter++ == 60) break;
          float g = (d[l + 1] - d[l]) / (2.f * e[l]);
          float rr = sqrtf(g * g + 1.f);
          g = d[m] - d[l] + e[l] / (g + copysignf(rr, g));
          float sn = 1.f, cs = 1.f, p = 0.f;
          int i;
          for (i = m - 1; i >= l; --i) {
            float f = sn * e[i];
            float b = cs * e[i];
            rr = sqrtf(f * f + g * g);
            e[i + 1] = rr;
            if (rr == 0.f) { d[i + 1] -= p; e[m] = 0.f; break; }
            sn = f / rr;
            cs = g / rr;
            g = d[i + 1] - p;
            rr = (d[i] - g) * sn + 2.f * cs * b;
            p = sn * rr;
            d[i + 1] = g + p;
            g = cs * rr - b;
            float zi1 = z[i + 1];
            z[i + 1] = sn * z[i] + cs * zi1;
            z[i] = cs * z[i] - sn * zi1;
          }
          if (rr == 0.f && i >= l) continue;
          d[l] -= p;
          e[l] = g;
          e[m] = 0.f;
        }
      } while (m != l);
    }
    for (int k = 0; k < PITER; ++k) {
      float lam = d[k] > 1e-12f ? d[k] : 1e-12f;
      quad += z[k] * z[k] * logf(lam);
    }
  }
  sdata[t] = quad;
  __syncthreads();
  for (int st = 128; st > 0; st >>= 1) {
    if (t < st) sdata[t] += sdata[t + st];
    __syncthreads();
  }
  if (t == 0) {
    float logdet = (float)NN * (sdata[0] * 0.01f);
    out[0] = -0.5f * ydot - 0.5f * logdet - (float)NN * 0.5f * 1.8378770664093454f;
  }
}

extern "C" void kernel_launch(void* const* d_in, const int* in_sizes, int n_in,
                              void* d_out, int out_size, void* d_ws, size_t ws_size,
                              hipStream_t stream) {
  const float* K = (const float*)d_in[0];
  const float* y = (const float*)d_in[1];
  const float* Z = (const float*)d_in[2];
  float* out = (float*)d_out;
  char* ws = (char*)d_ws;
  if (ws_size < 161018368ull) return;  // need ~153.6 MiB

  unsigned short* Kb = (unsigned short*)(ws + 0ull);           // 134,217,728
  unsigned short* Pb = (unsigned short*)(ws + 134217728ull);   //   2,097,152 (128 cols)
  float* P  = (float*)(ws + 136314880ull);                     //   3,309,568 (101 cols)
  float* R  = (float*)(ws + 139624448ull);                     //   3,309,568
  float* V  = (float*)(ws + 142934016ull);                     //   3,309,568
  float* Vp = (float*)(ws + 146243584ull);                     //  14,680,064 (4 x 112 cols)
  float* X0 = (float*)(ws + 160923648ull);                     //      32,768
  float* RS = (float*)(ws + 160956416ull);                     // rs[31][128]
  float* PV = (float*)(ws + 160972288ull);                     // pv[30][128]
  float* AL = (float*)(ws + 160987648ull);                     // alphas[30][128]
  float* BE = (float*)(ws + 161003008ull);                     // betas[30][128]

  cast_k_kernel<<<8192, 256, 0, stream>>>(K, Kb);
  init_vec_kernel<<<dim3(32, 101), 256, 0, stream>>>(y, Z, P, R, Pb);
  init_misc_kernel<<<240, 256, 0, stream>>>(X0, RS, Pb + (size_t)NCOLS * NN);
  init_rs_kernel<<<1, 256, 0, stream>>>(y, RS);

  for (int it = 0; it < PITER; ++it) {
    gemm_kernel<<<512, 256, 0, stream>>>(Kb, Pb, Vp);
    reduce_pv_kernel<<<dim3(8, 101), 256, 0, stream>>>(Vp, P, V, PV + it * 128);
    update1_kernel<<<dim3(8, 101), 256, 0, stream>>>(V, P, R, X0, PV + it * 128,
        RS + it * 128, RS + (it + 1) * 128, AL + it * 128);
    update2_kernel<<<dim3(8, 101), 256, 0, stream>>>(R, P, Pb, RS + it * 128,
        RS + (it + 1) * 128, BE + it * 128);
  }
  final_kernel<<<1, 256, 0, stream>>>(y, X0, AL, BE, out);
}

// Round 2
// 2092.619 us; speedup vs baseline: 1.4813x; 1.4813x over previous
//
#include <hip/hip_runtime.h>
#include <hip/hip_bf16.h>

#define NN 8192
#define NCOLS 101      // y + 100 probes
#define CPW 112        // compute columns (7 x 16)
#define CPAD 128       // staged columns (zero-padded)
#define BM 64
#define BK 64
#define KSPL 4
#define KCH (NN / KSPL)    // 2048
#define NSTEP (KCH / BK)   // 32
#define PITER 30

typedef __attribute__((ext_vector_type(8))) short bf16x8;
typedef __attribute__((ext_vector_type(4))) float f32x4;

__device__ __forceinline__ unsigned short f2bf(float f) {
  __hip_bfloat16 h = __float2bfloat16(f);
  return *reinterpret_cast<unsigned short*>(&h);
}

__device__ __forceinline__ void async_copy16(const void* g, void* l) {
  __builtin_amdgcn_global_load_lds(
      (const __attribute__((address_space(1))) unsigned int*)g,
      (__attribute__((address_space(3))) unsigned int*)l, 16, 0, 0);
}

// valid result on thread 0 only
__device__ __forceinline__ float block_sum(float v) {
  #pragma unroll
  for (int o = 32; o > 0; o >>= 1) v += __shfl_down(v, o);
  __shared__ float sw[4];
  int w = threadIdx.x >> 6;
  if ((threadIdx.x & 63) == 0) sw[w] = v;
  __syncthreads();
  float r = 0.f;
  if (threadIdx.x < 4) r = sw[threadIdx.x];
  r += __shfl_down(r, 2);
  r += __shfl_down(r, 1);
  return r;
}

// ---------------- GEMM: Vpart[kz] = K[rb rows] @ P (bf16 MFMA) ----------------
// LDS layout: sA[row][kslot] where kslot = seg ^ (row&7)  (seg = 16B segment of 8 bf16)
__global__ __launch_bounds__(256, 2) void gemm_kernel(
    const unsigned short* __restrict__ Kb,
    const unsigned short* __restrict__ Pb,
    float* __restrict__ Vp) {
  __shared__ __align__(16) unsigned short sA[BM * BK];     // 8 KB
  __shared__ __align__(16) unsigned short sB[CPAD * BK];   // 16 KB
  __shared__ __align__(16) float sC[BM * 113];             // 28.9 KB

  int bx = blockIdx.x;
  int rb = bx & 127;
  int kz = bx >> 7;
  int tid = threadIdx.x;
  int lane = tid & 63;
  int w = tid >> 6;
  int r0 = rb * BM;
  int k0 = kz * KCH;
  int lrow = lane >> 3;   // 0..7
  int lseg = lane & 7;    // LDS 16B slot within row

  f32x4 acc[7];
  #pragma unroll
  for (int i = 0; i < 7; ++i) acc[i] = (f32x4){0.f, 0.f, 0.f, 0.f};

  int mm = lane & 15;
  int quad = lane >> 4;

  for (int s = 0; s < NSTEP; ++s) {
    int kk = k0 + s * BK;
    int gseg = lseg ^ lrow;
    #pragma unroll
    for (int q = 0; q < 2; ++q) {
      int rl = w * 16 + q * 8 + lrow;
      const unsigned short* g = Kb + (size_t)(r0 + rl) * NN + kk + gseg * 8;
      async_copy16(g, (char*)sA + (size_t)(w * 16 + q * 8) * 128);
    }
    #pragma unroll
    for (int q = 0; q < 4; ++q) {
      int cl = w * 32 + q * 8 + lrow;
      const unsigned short* g = Pb + (size_t)cl * NN + kk + gseg * 8;
      async_copy16(g, (char*)sB + (size_t)(w * 32 + q * 8) * 128);
    }
    __syncthreads();
    const bf16x8* sAv = (const bf16x8*)sA;
    const bf16x8* sBv = (const bf16x8*)sB;
    int arow = w * 16 + mm;
    #pragma unroll
    for (int kh = 0; kh < 2; ++kh) {
      int sidx = kh * 4 + quad;
      bf16x8 aF = sAv[arow * 8 + (sidx ^ (arow & 7))];
      #pragma unroll
      for (int ct = 0; ct < 7; ++ct) {
        int bcol = ct * 16 + mm;
        bf16x8 bF = sBv[bcol * 8 + (sidx ^ (bcol & 7))];
        acc[ct] = __builtin_amdgcn_mfma_f32_16x16x32_bf16(aF, bF, acc[ct], 0, 0, 0);
      }
    }
    __syncthreads();
  }
  #pragma unroll
  for (int ct = 0; ct < 7; ++ct)
    #pragma unroll
    for (int r = 0; r < 4; ++r)
      sC[(w * 16 + quad * 4 + r) * 113 + ct * 16 + mm] = acc[ct][r];
  __syncthreads();
  float* Vout = Vp + (size_t)kz * ((size_t)CPW * NN);
  for (int idx = tid; idx < BM * CPW; idx += 256) {
    int col = idx >> 6;
    int row = idx & 63;
    if (col < NCOLS)
      Vout[(size_t)col * NN + r0 + row] = sC[row * 113 + col];
  }
}

// ---------------- V = sum of 4 partials; pv[c] += sum(P.*V) ----------------
__global__ void reduce_pv_kernel(const float* __restrict__ Vp,
                                 const float* __restrict__ P,
                                 float* __restrict__ V,
                                 float* __restrict__ pv) {
  const size_t SPL = (size_t)CPW * NN;
  int c = blockIdx.y;
  size_t off = (size_t)c * NN + blockIdx.x * 1024 + threadIdx.x * 4;
  float4 a = *(const float4*)(Vp + off);
  float4 b = *(const float4*)(Vp + SPL + off);
  float4 d = *(const float4*)(Vp + 2 * SPL + off);
  float4 e = *(const float4*)(Vp + 3 * SPL + off);
  float4 v;
  v.x = a.x + b.x + d.x + e.x;
  v.y = a.y + b.y + d.y + e.y;
  v.z = a.z + b.z + d.z + e.z;
  v.w = a.w + b.w + d.w + e.w;
  *(float4*)(V + off) = v;
  float4 p = *(const float4*)(P + off);
  float dot = p.x * v.x + p.y * v.y + p.z * v.z + p.w * v.w;
  float tot = block_sum(dot);
  if (threadIdx.x == 0) atomicAdd(pv + c, tot);
}

// ---------------- alpha; X0 += a*P(:,0); R -= a*V; rs_new += |R|^2 ----------------
__global__ void update1_kernel(const float* __restrict__ V,
                               const float* __restrict__ P,
                               float* __restrict__ R,
                               float* __restrict__ X0,
                               const float* __restrict__ pv,
                               const float* __restrict__ rs,
                               float* __restrict__ rs_new,
                               float* __restrict__ alphas) {
  int c = blockIdx.y;
  float alpha = rs[c] / pv[c];
  size_t off = (size_t)c * NN + blockIdx.x * 1024 + threadIdx.x * 4;
  float4 r = *(float4*)(R + off);
  float4 v = *(const float4*)(V + off);
  r.x -= alpha * v.x; r.y -= alpha * v.y; r.z -= alpha * v.z; r.w -= alpha * v.w;
  *(float4*)(R + off) = r;
  if (c == 0) {
    size_t xo = blockIdx.x * 1024 + threadIdx.x * 4;
    float4 x = *(float4*)(X0 + xo);
    float4 p = *(const float4*)(P + off);
    x.x += alpha * p.x; x.y += alpha * p.y; x.z += alpha * p.z; x.w += alpha * p.w;
    *(float4*)(X0 + xo) = x;
  }
  float rn = r.x * r.x + r.y * r.y + r.z * r.z + r.w * r.w;
  float tot = block_sum(rn);
  if (threadIdx.x == 0) {
    atomicAdd(rs_new + c, tot);
    if (blockIdx.x == 0) alphas[c] = alpha;
  }
}

// ---------------- beta; P = R + b*P; Pb = bf16(P) ----------------
__global__ void update2_kernel(const float* __restrict__ R,
                               float* __restrict__ P,
                               unsigned short* __restrict__ Pb,
                               const float* __restrict__ rs,
                               const float* __restrict__ rs_new,
                               float* __restrict__ betas) {
  int c = blockIdx.y;
  float beta = rs_new[c] / rs[c];
  size_t off = (size_t)c * NN + blockIdx.x * 1024 + threadIdx.x * 4;
  float4 r = *(const float4*)(R + off);
  float4 p = *(float4*)(P + off);
  p.x = r.x + beta * p.x; p.y = r.y + beta * p.y;
  p.z = r.z + beta * p.z; p.w = r.w + beta * p.w;
  *(float4*)(P + off) = p;
  ushort4 u;
  u.x = f2bf(p.x); u.y = f2bf(p.y); u.z = f2bf(p.z); u.w = f2bf(p.w);
  *(ushort4*)(Pb + off) = u;
  if (threadIdx.x == 0 && blockIdx.x == 0) betas[c] = beta;
}

// ---------------- init ----------------
__global__ void cast_k_kernel(const float* __restrict__ K, unsigned short* __restrict__ Kb) {
  size_t i = ((size_t)blockIdx.x * 256 + threadIdx.x) * 4;
  size_t stride = (size_t)gridDim.x * 1024;
  for (; i < (size_t)NN * NN; i += stride) {
    float4 f = *(const float4*)(K + i);
    ushort4 u;
    u.x = f2bf(f.x); u.y = f2bf(f.y); u.z = f2bf(f.z); u.w = f2bf(f.w);
    *(ushort4*)(Kb + i) = u;
  }
}

__global__ void init_vec_kernel(const float* __restrict__ y, const float* __restrict__ Z,
                                float* __restrict__ P, float* __restrict__ R,
                                unsigned short* __restrict__ Pb) {
  int c = blockIdx.y;
  int i = blockIdx.x * 256 + threadIdx.x;
  float val = (c == 0) ? y[i] : Z[(size_t)i * 100 + (c - 1)];
  size_t off = (size_t)c * NN + i;
  P[off] = val;
  R[off] = val;
  Pb[off] = f2bf(val);
}

__global__ void init_misc_kernel(float* __restrict__ X0, float* __restrict__ smalls,
                                 unsigned short* __restrict__ Pbpad) {
  const int total = 8192 + 15488 + 27 * NN;
  for (int t = blockIdx.x * 256 + threadIdx.x; t < total; t += gridDim.x * 256) {
    if (t < 8192) X0[t] = 0.f;
    else if (t < 8192 + 15488) smalls[t - 8192] = 0.f;
    else Pbpad[t - (8192 + 15488)] = 0;
  }
}

__global__ void init_rs_kernel(const float* __restrict__ y, float* __restrict__ rs0) {
  int t = threadIdx.x;
  float s = 0.f;
  for (int i = t; i < NN; i += 256) { float v = y[i]; s += v * v; }
  float tot = block_sum(s);
  if (t == 0) rs0[0] = tot;
  if (t >= 1 && t <= 100) rs0[t] = (float)NN;
}

// ---------------- SLQ: Sturm bisection + Gauss-weight recurrence, fp64 ----------------
// One block per probe (64 threads, 1 wave). Lane k (k<30) finds eigenvalue k of the
// 30x30 tridiagonal T and its Gauss weight w_k = 1/sum_j v_j(lam_k)^2, then the wave
// reduces sum_k w_k*log(lam_k) -> QP[probe]. All loops have constant trip counts so
// d[]/e[] stay in VGPRs (no scratch, no dynamic indexing, no divergence).
__global__ __launch_bounds__(64, 1) void slq_kernel(
    const float* __restrict__ AL, const float* __restrict__ BE,
    float* __restrict__ QP) {
  __shared__ double sd[PITER], se[PITER];
  int lane = threadIdx.x;
  int c = blockIdx.x + 1;  // probe column in AL/BE (col 0 is y)
  if (lane < PITER) {
    double a = (double)AL[lane * 128 + c];
    double dd = 1.0 / a;
    if (lane > 0) {
      double ap = (double)AL[(lane - 1) * 128 + c];
      double bp = (double)BE[(lane - 1) * 128 + c];
      dd += bp / ap;
    }
    sd[lane] = dd;
    double ee = 0.0;
    if (lane < PITER - 1) {
      double b = (double)BE[lane * 128 + c];
      ee = sqrt(b) / a;
    }
    se[lane] = ee;
  }
  __syncthreads();

  // copy T into registers (constant indices -> VGPR-resident)
  double d[PITER], e[PITER];
  #pragma unroll
  for (int i = 0; i < PITER; ++i) { d[i] = sd[i]; e[i] = se[i]; }

  float quadk = 0.f;
  if (lane < PITER) {
    // Gershgorin bounds
    double lo = 1e300, hi = -1e300;
    #pragma unroll
    for (int i = 0; i < PITER; ++i) {
      double r = e[i] + (i > 0 ? e[i - 1] : 0.0);
      lo = fmin(lo, d[i] - r);
      hi = fmax(hi, d[i] + r);
    }
    int k = lane;
    // bisection on Sturm count
    for (int it = 0; it < 48; ++it) {
      double mid = 0.5 * (lo + hi);
      int cnt = 0;
      double q = d[0] - mid;
      cnt += (q < 0.0);
      #pragma unroll
      for (int i = 1; i < PITER; ++i) {
        double aq = fabs(q);
        if (aq < 1e-30) q = (q < 0.0) ? -1e-30 : 1e-30;
        q = d[i] - mid - (e[i - 1] * e[i - 1]) / q;
        cnt += (q < 0.0);
      }
      if (cnt > k) hi = mid; else lo = mid;
    }
    double lam = 0.5 * (lo + hi);
    // first-component Gauss weight via 3-term eigenvector recurrence
    double e0 = fmax(e[0], 1e-150);
    double vprev = 1.0;
    double vcur = (lam - d[0]) / e0;
    double s = 1.0 + vcur * vcur;
    double scale2 = 1.0;
    #pragma unroll
    for (int i = 1; i < PITER - 1; ++i) {
      double ei = fmax(e[i], 1e-150);
      double vnext = ((lam - d[i]) * vcur - e[i - 1] * vprev) / ei;
      if (fabs(vnext) > 1e150) {
        vnext *= 1e-150; vcur *= 1e-150; s *= 1e-300; scale2 *= 1e-300;
      }
      vprev = vcur; vcur = vnext;
      s += vcur * vcur;
    }
    double w = scale2 / s;
    double lc = lam > 1e-12 ? lam : 1e-12;
    quadk = (float)(w * log(lc));
  }
  #pragma unroll
  for (int o = 32; o > 0; o >>= 1) quadk += __shfl_down(quadk, o);
  if (lane == 0) QP[blockIdx.x] = quadk;
}

// ---------------- final: ydot + combine ----------------
__global__ void final2_kernel(const float* __restrict__ y, const float* __restrict__ X0,
                              const float* __restrict__ QP, float* __restrict__ out) {
  int t = threadIdx.x;
  float s = 0.f;
  for (int i = t; i < NN; i += 256) s += y[i] * X0[i];
  float ydot = block_sum(s);
  __syncthreads();
  float q = (t < 100) ? QP[t] : 0.f;
  float qsum = block_sum(q);
  if (t == 0) {
    float logdet = (float)NN * (qsum * 0.01f);
    out[0] = -0.5f * ydot - 0.5f * logdet - (float)NN * 0.5f * 1.8378770664093454f;
  }
}

extern "C" void kernel_launch(void* const* d_in, const int* in_sizes, int n_in,
                              void* d_out, int out_size, void* d_ws, size_t ws_size,
                              hipStream_t stream) {
  const float* K = (const float*)d_in[0];
  const float* y = (const float*)d_in[1];
  const float* Z = (const float*)d_in[2];
  float* out = (float*)d_out;
  char* ws = (char*)d_ws;
  if (ws_size < 161018368ull) return;  // need ~153.6 MiB

  unsigned short* Kb = (unsigned short*)(ws + 0ull);           // 134,217,728
  unsigned short* Pb = (unsigned short*)(ws + 134217728ull);   //   2,097,152 (128 cols)
  float* P  = (float*)(ws + 136314880ull);                     //   3,309,568 (101 cols)
  float* R  = (float*)(ws + 139624448ull);                     //   3,309,568
  float* V  = (float*)(ws + 142934016ull);                     //   3,309,568
  float* Vp = (float*)(ws + 146243584ull);                     //  14,680,064 (4 x 112 cols)
  float* X0 = (float*)(ws + 160923648ull);                     //      32,768
  float* RS = (float*)(ws + 160956416ull);                     // rs[31][128]
  float* PV = (float*)(ws + 160972288ull);                     // pv[30][128]
  float* AL = (float*)(ws + 160987648ull);                     // alphas[30][128]
  float* BE = (float*)(ws + 161003008ull);                     // betas[30][128]
  float* QP = Vp;                                              // 100 floats, reused after loop

  cast_k_kernel<<<8192, 256, 0, stream>>>(K, Kb);
  init_vec_kernel<<<dim3(32, 101), 256, 0, stream>>>(y, Z, P, R, Pb);
  init_misc_kernel<<<240, 256, 0, stream>>>(X0, RS, Pb + (size_t)NCOLS * NN);
  init_rs_kernel<<<1, 256, 0, stream>>>(y, RS);

  for (int it = 0; it < PITER; ++it) {
    gemm_kernel<<<512, 256, 0, stream>>>(Kb, Pb, Vp);
    reduce_pv_kernel<<<dim3(8, 101), 256, 0, stream>>>(Vp, P, V, PV + it * 128);
    update1_kernel<<<dim3(8, 101), 256, 0, stream>>>(V, P, R, X0, PV + it * 128,
        RS + it * 128, RS + (it + 1) * 128, AL + it * 128);
    update2_kernel<<<dim3(8, 101), 256, 0, stream>>>(R, P, Pb, RS + it * 128,
        RS + (it + 1) * 128, BE + it * 128);
  }
  slq_kernel<<<100, 64, 0, stream>>>(AL, BE, QP);
  final2_kernel<<<1, 256, 0, stream>>>(y, X0, QP, out);
}